// Round 4
// baseline (104.162 us; speedup 1.0000x reference)
//
#include <hip/hip_runtime.h>

// RNNT (Transducer) alpha-recursion loss, forward, mean reduction.
// B=4, T=512, U=100 (U+1=101 cols), V=1024, fp32.
//
// alpha[t][u] = lse(alpha[t-1][u] + blank[t-1][u], alpha[t][u-1] + emit[t][u-1])
// out = mean_b( -alpha[Tb-1][Ub] )
//
// SINGLE fused kernel (R4): per-kernel graph-node boundaries cost ~30-40us
// each on this part (R1->R2 evidence), so gather + grid-barrier + DP live in
// one dispatch.
//   Phase 1 (all 256 blocks x 256 thr): scatter-gather blank (v=0) and
//     emit (v=label) into anti-diagonal-major float4 rows g_PK (log2-scaled),
//     rectangle-masked to cells that can reach alpha[Tb-1][Ub].
//     slot = tid>>6 == batch b; block x handles rows r = x, x+256, x+512.
//   Software grid barrier: agent-scope release arrive by every block; only
//     blocks 0..3 spin (acquire). Residency guaranteed: __launch_bounds__
//     (256,4) -> VGPR<=128 -> >=4 blocks/CU -> >=1024 co-resident >= 256.
//   Phase 2 (blocks 0..3, wave 0): wavefront DP, lane l owns columns
//     u=2l,2l+1; cross-lane via DPP wave_shr:1; PF=8 static prefetch.
//     Last finisher reduces g_ps -> out and resets barrier/counter state.

constexpr int B = 4, T = 512, U = 100, Up1 = 101, V = 1024;
constexpr int DIAGS = T + U;       // 612
constexpr int PF = 8;
constexpr int GRID = 256;
constexpr float NEG = -1e30f;
constexpr float LOG2E = 1.44269504088896340736f;
constexpr float LN2 = 0.69314718055994530942f;

__device__ float4 g_PK[(size_t)B * DIAGS * 64];
__device__ float g_ps[B];
__device__ int g_bar = 0;
__device__ int g_ctr = 0;

__device__ __forceinline__ int clampi(int x, int lo, int hi) {
  return x < lo ? lo : (x > hi ? hi : x);
}
__device__ __forceinline__ float fexp2(float x) {
  float r; asm("v_exp_f32 %0, %1" : "=v"(r) : "v"(x)); return r;
}
__device__ __forceinline__ float flog2(float x) {
  float r; asm("v_log_f32 %0, %1" : "=v"(r) : "v"(x)); return r;
}
// log2-domain logaddexp: max(a,b) + log2(1 + 2^(-|a-b|))
__device__ __forceinline__ float lse2(float a, float b) {
  float m = fmaxf(a, b);
  float d = a - b;
  float nd = fminf(d, -d);        // -|a-b|
  return m + flog2(1.0f + fexp2(nd));
}
// whole-wave shift: lane l receives lane l-1 (lane 0 keeps own; unused)
__device__ __forceinline__ float wave_shr1(float x) {
  int xi = __builtin_bit_cast(int, x);
  int r = __builtin_amdgcn_update_dpp(xi, xi, 0x138 /*WF_SR1*/, 0xF, 0xF, false);
  return __builtin_bit_cast(float, r);
}

__global__ __launch_bounds__(256, 4)
void fused_kernel(const float* __restrict__ logits,
                  const int* __restrict__ labels,
                  const int* __restrict__ logit_len,
                  const int* __restrict__ label_len,
                  float* __restrict__ out) {
  const int lane = threadIdx.x & 63;
  const int slot = threadIdx.x >> 6;     // == batch b for the gather phase

  // ---------------- Phase 1: gather ----------------
  {
    const int b = slot;
    const int Tb = clampi(logit_len[b], 1, T);
    const int Ub = clampi(label_len[b], 1, U);
    const int smax = Tb - 1 + Ub;
    const float* lg = logits + (size_t)b * T * Up1 * V;
    const int u0 = 2 * lane, u1 = u0 + 1;
    // labels needed by this lane are fixed: u0-1 and u0
    int labz = 0, labw = 0;
    if (u0 >= 1 && u0 <= U) labz = clampi(labels[b * U + (u0 - 1)], 0, V - 1);
    if (u0 < U)             labw = clampi(labels[b * U + u0], 0, V - 1);

    for (int r = blockIdx.x; r < DIAGS; r += GRID) {
      if (r > smax) continue;            // never consumed
      float4 v; v.x = v.y = v.z = v.w = NEG;
      int tx = r - u0;                   // blank[tx][u0], u<=Ub, t<=Tb-1
      if (u0 <= Ub && tx >= 0 && tx <= Tb - 1)
        v.x = LOG2E * lg[((size_t)tx * Up1 + u0) * V];
      int ty = r - u1;                   // blank[ty][u1]
      if (u1 <= Ub && ty >= 0 && ty <= Tb - 1)
        v.y = LOG2E * lg[((size_t)ty * Up1 + u1) * V];
      int tz = r - u0 + 1;               // emit[tz][u0-1], u-1<=Ub-1
      if (u0 >= 1 && u0 <= Ub && tz >= 0 && tz <= Tb - 1)
        v.z = LOG2E * lg[((size_t)tz * Up1 + (u0 - 1)) * V + labz];
      int tw = r - u0;                   // emit[tw][u0]
      if (u0 <= Ub - 1 && tw >= 0 && tw <= Tb - 1)
        v.w = LOG2E * lg[((size_t)tw * Up1 + u0) * V + labw];
      g_PK[((size_t)b * DIAGS + r) * 64 + lane] = v;
    }
  }

  // ---------------- Grid barrier ----------------
  __syncthreads();
  if (threadIdx.x == 0) {
    __hip_atomic_fetch_add(&g_bar, 1, __ATOMIC_ACQ_REL, __HIP_MEMORY_SCOPE_AGENT);
    if (blockIdx.x < B) {
      while (__hip_atomic_load(&g_bar, __ATOMIC_ACQUIRE, __HIP_MEMORY_SCOPE_AGENT) < GRID)
        __builtin_amdgcn_s_sleep(2);
    }
  }
  __syncthreads();
  if (blockIdx.x >= B || threadIdx.x >= 64) return;

  // ---------------- Phase 2: DP (blocks 0..3, wave 0) ----------------
  const int b = blockIdx.x;
  const int Tb = clampi(logit_len[b], 1, T);
  const int Ub = clampi(label_len[b], 1, U);
  const int smax = Tb - 1 + Ub;          // diagonal of the answer cell

  const float4* PK = g_PK + (size_t)b * DIAGS * 64;

  float first = NEG;                     // alpha[.][2*lane]
  float second = NEG;                    // alpha[.][2*lane+1]

  float4 p[PF], n[PF];
#pragma unroll
  for (int j = 0; j < PF; ++j) {
    int r = j - 1; if (r < 0) r = 0;     // step-0 row is don't-care (masked)
    p[j] = PK[r * 64 + lane];
  }

  for (int s0 = 0; s0 <= smax; s0 += PF) {
#pragma unroll
    for (int j = 0; j < PF; ++j) {
      int r = s0 + PF + j - 1;
      if (r < DIAGS) n[j] = PK[r * 64 + lane];
      else           n[j] = make_float4(NEG, NEG, NEG, NEG);
    }
#pragma unroll
    for (int j = 0; j < PF; ++j) {
      int s = s0 + j;
      if (s <= smax) {                   // wave-uniform branch
        float pfB = wave_shr1(second);   // neighbor's odd column, pre-update
        float oldA = first;
        int tA = s - 2 * lane;
        // column A: u = 2*lane (lanes 0..50)
        if (lane <= U / 2 && tA >= 0 && tA < T) {
          float up = (tA > 0) ? first + p[j].x : NEG;
          float lf = (lane > 0) ? pfB + p[j].z : NEG;
          float v = lse2(up, lf);
          if ((tA | lane) == 0) v = 0.0f;  // alpha[0][0] = 0
          first = v;
          if (tA == Tb - 1 && 2 * lane == Ub)
            __hip_atomic_store(&g_ps[b], v, __ATOMIC_RELEASE, __HIP_MEMORY_SCOPE_AGENT);
        }
        // column B: u = 2*lane+1 (lanes 0..49)
        int tB = tA - 1;
        if (lane <= (U - 2) / 2 && tB >= 0 && tB < T) {
          float up = (tB > 0) ? second + p[j].y : NEG;
          float lf = oldA + p[j].w;
          float v = lse2(up, lf);
          second = v;
          if (tB == Tb - 1 && 2 * lane + 1 == Ub)
            __hip_atomic_store(&g_ps[b], v, __ATOMIC_RELEASE, __HIP_MEMORY_SCOPE_AGENT);
        }
      }
    }
#pragma unroll
    for (int j = 0; j < PF; ++j) p[j] = n[j];
  }

  // last DP block to finish computes the mean and resets barrier state
  if (lane == 0) {
    int old = __hip_atomic_fetch_add(&g_ctr, 1, __ATOMIC_ACQ_REL, __HIP_MEMORY_SCOPE_AGENT);
    if (old == B - 1) {
      float s = 0.0f;
      for (int i = 0; i < B; ++i)
        s += __hip_atomic_load(&g_ps[i], __ATOMIC_ACQUIRE, __HIP_MEMORY_SCOPE_AGENT);
      out[0] = -s * (LN2 / B);
      __hip_atomic_store(&g_ctr, 0, __ATOMIC_RELAXED, __HIP_MEMORY_SCOPE_AGENT);
      __hip_atomic_store(&g_bar, 0, __ATOMIC_RELAXED, __HIP_MEMORY_SCOPE_AGENT);
    }
  }
}

extern "C" void kernel_launch(void* const* d_in, const int* in_sizes, int n_in,
                              void* d_out, int out_size, void* d_ws, size_t ws_size,
                              hipStream_t stream) {
  const float* logits = (const float*)d_in[0];
  const int* labels = (const int*)d_in[1];
  const int* logit_len = (const int*)d_in[2];
  const int* label_len = (const int*)d_in[3];
  float* out = (float*)d_out;

  hipLaunchKernelGGL(fused_kernel, dim3(GRID), dim3(256), 0, stream,
                     logits, labels, logit_len, label_len, out);
}